// Round 4
// baseline (751.144 us; speedup 1.0000x reference)
//
#include <hip/hip_runtime.h>
#include <hip/hip_bf16.h>

// Problem constants (reference: R=8, N=4096, IN_F=OUT_F=64)
#define RR 8
#define NN 4096
#define FF 64

typedef float f32x4 __attribute__((ext_vector_type(4)));
typedef short bf16x8 __attribute__((ext_vector_type(8)));

__device__ __forceinline__ short f2b(float f) {
  __hip_bfloat16 h = __float2bfloat16(f);
  return __builtin_bit_cast(short, h);
}

__device__ __forceinline__ bf16x8 cvt8(f32x4 lo, f32x4 hi) {
  bf16x8 r;
  r[0] = f2b(lo[0]); r[1] = f2b(lo[1]); r[2] = f2b(lo[2]); r[3] = f2b(lo[3]);
  r[4] = f2b(hi[0]); r[5] = f2b(hi[1]); r[6] = f2b(hi[2]); r[7] = f2b(hi[3]);
  return r;
}

// ---------------------------------------------------------------------------
// Kernel 1: Zt[r][o][m] = sum_i W[r][o][i] * x[m][i], stored bf16 in d_ws.
// (unchanged — verified correct)
__global__ __launch_bounds__(256) void compute_zt(const float* __restrict__ x,
                                                  const float* __restrict__ w,
                                                  short* __restrict__ zt) {
  const int tid   = threadIdx.x;
  const int lane  = tid & 63;
  const int wv    = tid >> 6;
  const int row16 = lane & 15;
  const int quad  = lane >> 4;
  const int r     = blockIdx.y;
  const int m0    = blockIdx.x * 64 + wv * 16;

  bf16x8 bfr[2];
#pragma unroll
  for (int s = 0; s < 2; ++s) {
    const float* p = x + (size_t)(m0 + row16) * FF + s * 32 + quad * 8;
    bfr[s] = cvt8(*(const f32x4*)p, *(const f32x4*)(p + 4));
  }

  f32x4 acc[4] = {{0.f,0.f,0.f,0.f},{0.f,0.f,0.f,0.f},
                  {0.f,0.f,0.f,0.f},{0.f,0.f,0.f,0.f}};
#pragma unroll
  for (int og = 0; og < 4; ++og) {
#pragma unroll
    for (int s = 0; s < 2; ++s) {
      const float* p = w + ((size_t)r * FF + og * 16 + row16) * FF + s * 32 + quad * 8;
      bf16x8 afr = cvt8(*(const f32x4*)p, *(const f32x4*)(p + 4));
      acc[og] = __builtin_amdgcn_mfma_f32_16x16x32_bf16(afr, bfr[s], acc[og], 0, 0, 0);
    }
  }

#pragma unroll
  for (int og = 0; og < 4; ++og)
#pragma unroll
    for (int j = 0; j < 4; ++j) {
      int o = og * 16 + quad * 4 + j;
      int m = m0 + row16;
      zt[((size_t)r * FF + o) * NN + m] = f2b(acc[og][j]);
    }
}

// ---------------------------------------------------------------------------
// Kernel 2 (R2 rewrite, resubmitted after infra failure): BARRIER-FREE, LDS-FREE.
// partial[r*4+q][n][o] = sum_{m in quarter q} A[r][n][m] * Zt[r][o][m]
//
// Rationale: A is used once per element — LDS staging of A bought nothing
// and cost 16 barriers/block (4-wave lockstep), ds round-trips, and an
// 8-way read bank conflict. Two rounds of scheduling/L2 fixes were null:
// the lockstep structure itself was the bottleneck. Now each WAVE is an
// independent task: 32 n-rows x 1024 k. A-fragments are loaded directly
// from global in MFMA fragment shape (fp32 -> bf16 cvt in regs — the same
// f2b work writeA already paid), B-frags from L2-resident zt exactly as
// before. Register double-buffer, no __syncthreads anywhere, 4096
// free-running waves. Fragment layouts copied verbatim from the verified
// kernel:
//   A-frag: row = lane&15 (+16 for 2nd row-group), k = quad*8..+8
//   B-frag: o   = cg*16 + lane&15,                 k = quad*8..+8
//   C-out : n   = group*16 + quad*4 + j, o = cg*16 + lane&15
#define QK  1024                 // k-span per wave-task (quarter of a row)
#define NCH (QK / 32)            // 32 k-chunks of 32

struct FragSet {
  f32x4  aAlo, aAhi, aBlo, aBhi;   // A rows  n0+row16  and  n0+16+row16
  bf16x8 b0, b1, b2, b3;           // B o-groups 0..3
};

__device__ __forceinline__ void loadF(FragSet& F, const float* __restrict__ aA,
                                      const float* __restrict__ aB,
                                      const short* __restrict__ zb, int c) {
  const float* pa = aA + c * 32;
  F.aAlo = *(const f32x4*)pa;
  F.aAhi = *(const f32x4*)(pa + 4);
  const float* pb = aB + c * 32;
  F.aBlo = *(const f32x4*)pb;
  F.aBhi = *(const f32x4*)(pb + 4);
  const short* pz = zb + c * 32;
  F.b0 = *(const bf16x8*)pz;
  F.b1 = *(const bf16x8*)(pz + 16 * NN);
  F.b2 = *(const bf16x8*)(pz + 32 * NN);
  F.b3 = *(const bf16x8*)(pz + 48 * NN);
}

__device__ __forceinline__ void compF(const FragSet& F, f32x4* acc) {
  bf16x8 afA = cvt8(F.aAlo, F.aAhi);
  bf16x8 afB = cvt8(F.aBlo, F.aBhi);
  acc[0] = __builtin_amdgcn_mfma_f32_16x16x32_bf16(afA, F.b0, acc[0], 0, 0, 0);
  acc[1] = __builtin_amdgcn_mfma_f32_16x16x32_bf16(afA, F.b1, acc[1], 0, 0, 0);
  acc[2] = __builtin_amdgcn_mfma_f32_16x16x32_bf16(afA, F.b2, acc[2], 0, 0, 0);
  acc[3] = __builtin_amdgcn_mfma_f32_16x16x32_bf16(afA, F.b3, acc[3], 0, 0, 0);
  acc[4] = __builtin_amdgcn_mfma_f32_16x16x32_bf16(afB, F.b0, acc[4], 0, 0, 0);
  acc[5] = __builtin_amdgcn_mfma_f32_16x16x32_bf16(afB, F.b1, acc[5], 0, 0, 0);
  acc[6] = __builtin_amdgcn_mfma_f32_16x16x32_bf16(afB, F.b2, acc[6], 0, 0, 0);
  acc[7] = __builtin_amdgcn_mfma_f32_16x16x32_bf16(afB, F.b3, acc[7], 0, 0, 0);
}

__global__ __launch_bounds__(256, 4) void rgcn_main(const float* __restrict__ adj,
                                                    const short* __restrict__ zt,
                                                    float* __restrict__ partial) {
  const int tid   = threadIdx.x;
  const int lane  = tid & 63;
  const int wv    = tid >> 6;
  const int row16 = lane & 15;
  const int quad  = lane >> 4;

  // Task decode. r = bid&7 keeps one relation per XCD (round-robin dispatch
  // heuristic; harmless if mapping differs). Waves of a block share q and
  // take consecutive 32-row tiles -> identical zt stream (L1 reuse) and a
  // contiguous 128-row A footprint.
  const int bid     = blockIdx.x;              // 0..1023
  const int r       = bid & 7;
  const int u       = (bid >> 3) * 4 + wv;     // 0..511
  const int q       = u >> 7;                  // 0..3 k-quarter
  const int rowtile = u & 127;                 // 0..127
  const int n0      = rowtile * 32;
  const int k0      = q * QK;

  const float* aA = adj + ((size_t)r * NN + n0 + row16) * NN + k0 + quad * 8;
  const float* aB = aA + (size_t)16 * NN;
  const short* zb = zt + ((size_t)r * FF + row16) * NN + k0 + quad * 8;

  f32x4 acc[8] = {{0.f,0.f,0.f,0.f},{0.f,0.f,0.f,0.f},{0.f,0.f,0.f,0.f},
                  {0.f,0.f,0.f,0.f},{0.f,0.f,0.f,0.f},{0.f,0.f,0.f,0.f},
                  {0.f,0.f,0.f,0.f},{0.f,0.f,0.f,0.f}};

  FragSet F0, F1;
  loadF(F0, aA, aB, zb, 0);
#pragma unroll 1
  for (int it = 0; it < NCH / 2 - 1; ++it) {
    loadF(F1, aA, aB, zb, 2 * it + 1);
    compF(F0, acc);
    loadF(F0, aA, aB, zb, 2 * it + 2);
    compF(F1, acc);
  }
  loadF(F1, aA, aB, zb, NCH - 1);
  compF(F0, acc);
  compF(F1, acc);

  // Epilogue: per-wave partial tile (32 rows x 64 o), coalesced 128B rows.
  float* pb = partial + ((size_t)(r * 4 + q) * NN + n0) * FF;
#pragma unroll
  for (int g = 0; g < 2; ++g)
#pragma unroll
    for (int cg = 0; cg < 4; ++cg)
#pragma unroll
      for (int j = 0; j < 4; ++j)
        pb[(size_t)(g * 16 + quad * 4 + j) * FF + cg * 16 + row16] = acc[g * 4 + cg][j];
}

// ---------------------------------------------------------------------------
// Kernel 3: out[n][o] = sum_{s=0..31} partial[s][n][o]   (f32x4 vectorized)
__global__ __launch_bounds__(256) void reduce_partials(const f32x4* __restrict__ p,
                                                       f32x4* __restrict__ out) {
  const int idx = blockIdx.x * 256 + threadIdx.x;   // 65536 f32x4 elements
  f32x4 s = {0.f, 0.f, 0.f, 0.f};
#pragma unroll
  for (int sl = 0; sl < 32; ++sl)
    s += p[(size_t)sl * (NN * FF / 4) + idx];
  out[idx] = s;
}

// ---------------------------------------------------------------------------
extern "C" void kernel_launch(void* const* d_in, const int* in_sizes, int n_in,
                              void* d_out, int out_size, void* d_ws, size_t ws_size,
                              hipStream_t stream) {
  const float* adj = (const float*)d_in[0];   // [8, 4096, 4096] fp32
  const float* x   = (const float*)d_in[1];   // [4096, 64] fp32
  const float* w   = (const float*)d_in[2];   // [8, 64, 64] fp32
  float* out = (float*)d_out;                 // [4096, 64] fp32

  short* zt      = (short*)d_ws;                            // 4 MiB
  float* partial = (float*)((char*)d_ws + (16u << 20));     // 32 MiB @ +16 MiB

  compute_zt<<<dim3(NN / 64, RR), 256, 0, stream>>>(x, w, zt);
  rgcn_main<<<dim3(1024), 256, 0, stream>>>(adj, zt, partial);
  reduce_partials<<<dim3(NN * FF / 4 / 256), 256, 0, stream>>>(
      (const f32x4*)partial, (f32x4*)out);
}